// Round 1
// baseline (1356.941 us; speedup 1.0000x reference)
//
#include <hip/hip_runtime.h>
#include <hip/hip_bf16.h>
#include <cstdint>
#include <cstddef>

#define NE 8          // experts
#define TK 2          // top-k
#define DM 1024       // hidden
#define IM 4096       // intermediate
#define NT 8192       // tokens (4*2048)
#define NS (NT*TK)    // total slots = 16384 (exact)
#define SCAP (NS+128) // padded rows for last-tile overhang

typedef __bf16 bf16_t;
typedef __bf16 bf16x8 __attribute__((ext_vector_type(8)));
typedef float f32x4 __attribute__((ext_vector_type(4)));

// async global->LDS, 16B per lane. LDS side must be wave-uniform base + lane*16.
__device__ __forceinline__ void async_cp16(const bf16_t* g, bf16_t* l) {
  __builtin_amdgcn_global_load_lds(
      (__attribute__((address_space(1))) void*)(const_cast<bf16_t*>(g)),
      (__attribute__((address_space(3))) void*)(l), 16, 0, 0);
}

// ---------------- transpose + fp32->bf16 convert: src [z][R][C] f32 -> dst [z][C][R] bf16
__global__ void transpose_cvt(const float* __restrict__ src, bf16_t* __restrict__ dst,
                              int R, int C) {
  __shared__ float t[32][33];
  int bx = blockIdx.x * 32, by = blockIdx.y * 32;
  size_t zb = (size_t)blockIdx.z * R * C;
  int tx = threadIdx.x, ty = threadIdx.y;   // 32 x 8
#pragma unroll
  for (int i = 0; i < 4; ++i)
    t[ty + i*8][tx] = src[zb + (size_t)(by + ty + i*8) * C + bx + tx];
  __syncthreads();
#pragma unroll
  for (int i = 0; i < 4; ++i)
    dst[zb + (size_t)(bx + ty + i*8) * R + by + tx] = (bf16_t)t[tx][ty + i*8];
}

// ---------------- router: logits, softmax, top-2, renorm; per-expert counts + prob sums
__global__ void router_kernel(const float* __restrict__ x, const float* __restrict__ wgate,
                              int* __restrict__ counts, float* __restrict__ prob_sum,
                              int* __restrict__ topk_idx, float* __restrict__ topk_w) {
  __shared__ float s_psum[NE];
  __shared__ int s_cnt[NE];
  int tid = threadIdx.x;
  if (tid < NE) { s_psum[tid] = 0.f; s_cnt[tid] = 0; }
  __syncthreads();
  int lane = tid & 63, wv = tid >> 6;
  for (int t = 0; t < 8; ++t) {             // 4 waves x 8 tokens = 32 tokens/block
    int n = blockIdx.x * 32 + wv * 8 + t;
    float acc[NE];
#pragma unroll
    for (int e = 0; e < NE; ++e) acc[e] = 0.f;
#pragma unroll
    for (int j = 0; j < 16; ++j) {
      int d = j * 64 + lane;
      float xv = x[(size_t)n * DM + d];
#pragma unroll
      for (int e = 0; e < NE; ++e) acc[e] += xv * wgate[e * DM + d];
    }
#pragma unroll
    for (int e = 0; e < NE; ++e) {
#pragma unroll
      for (int off = 32; off > 0; off >>= 1) acc[e] += __shfl_xor(acc[e], off);
    }
    if (lane == 0) {
      float mx = acc[0];
#pragma unroll
      for (int e = 1; e < NE; ++e) mx = fmaxf(mx, acc[e]);
      float p[NE], s = 0.f;
#pragma unroll
      for (int e = 0; e < NE; ++e) { p[e] = __expf(acc[e] - mx); s += p[e]; }
      float inv = 1.f / s;
#pragma unroll
      for (int e = 0; e < NE; ++e) p[e] *= inv;
      int i0 = 0;
      for (int e = 1; e < NE; ++e) if (p[e] > p[i0]) i0 = e;     // ties -> lower idx (matches top_k)
      int i1 = (i0 == 0) ? 1 : 0;
      for (int e = 0; e < NE; ++e) if (e != i0 && p[e] > p[i1]) i1 = e;
      float rs = 1.f / (p[i0] + p[i1]);
      topk_idx[n * 2 + 0] = i0; topk_idx[n * 2 + 1] = i1;
      topk_w[n * 2 + 0] = p[i0] * rs; topk_w[n * 2 + 1] = p[i1] * rs;
      atomicAdd(&s_cnt[i0], 1); atomicAdd(&s_cnt[i1], 1);
#pragma unroll
      for (int e = 0; e < NE; ++e) atomicAdd(&s_psum[e], p[e]);
    }
  }
  __syncthreads();
  if (tid < NE) { atomicAdd(&counts[tid], s_cnt[tid]); atomicAdd(&prob_sum[tid], s_psum[tid]); }
}

// ---------------- exclusive scan of counts (8 elems), cursors, aux loss
__global__ void scan_aux(const int* __restrict__ counts, const float* __restrict__ prob_sum,
                         int* __restrict__ offsets, int* __restrict__ cursors,
                         float* __restrict__ aux_out) {
  if (threadIdx.x == 0) {
    int off = 0;
    float aux = 0.f;
    for (int e = 0; e < NE; ++e) {
      offsets[e] = off; cursors[e] = off;
      float f = (float)counts[e] * (1.f / (float)NS);
      float p = prob_sum[e] * (1.f / (float)NT);
      aux += f * p;
      off += counts[e];
    }
    offsets[NE] = off;
    *aux_out = 0.02f * 8.f * aux;
  }
}

// ---------------- gather tokens into per-expert compact bf16 rows
__global__ void gather_kernel(const float* __restrict__ x, const int* __restrict__ topk_idx,
                              const float* __restrict__ topk_w, int* __restrict__ cursors,
                              int* __restrict__ slot_token, float* __restrict__ slot_w,
                              bf16_t* __restrict__ Xg) {
  int lane = threadIdx.x & 63, wv = threadIdx.x >> 6;
  int pair = blockIdx.x * 4 + wv;           // (token, k)
  int n = pair >> 1, k = pair & 1;
  int e = topk_idx[n * 2 + k];
  int slot = 0;
  if (lane == 0) slot = atomicAdd(&cursors[e], 1);
  slot = __shfl(slot, 0);
  if (lane == 0) { slot_token[slot] = n; slot_w[slot] = topk_w[n * 2 + k]; }
#pragma unroll
  for (int j = 0; j < 16; ++j) {
    int d = j * 64 + lane;
    Xg[(size_t)slot * DM + d] = (bf16_t)x[(size_t)n * DM + d];
  }
}

// ---------------- GEMM1: H = silu(Xg @ WgT') * (Xg @ WuT')  per expert, bf16 MFMA
__global__ __launch_bounds__(256, 2) void gemm1_kernel(
    const bf16_t* __restrict__ Xg, const bf16_t* __restrict__ Wgt,
    const bf16_t* __restrict__ Wut, bf16_t* __restrict__ H,
    const int* __restrict__ offsets) {
  int e = blockIdx.z, mt = blockIdx.y, nt = blockIdx.x;
  int row0 = offsets[e], ne = offsets[e + 1] - row0;
  if (mt * 128 >= ne) return;
  int m0 = row0 + mt * 128;
  int n0 = nt * 128;

  __shared__ bf16_t sA[128 * 64];
  __shared__ bf16_t sG[128 * 64];
  __shared__ bf16_t sU[128 * 64];

  int tid = threadIdx.x, lane = tid & 63, wv = tid >> 6;
  int fm = lane & 15, fq = lane >> 4;
  int wm = (wv & 1) * 64, wn = (wv >> 1) * 64;

  f32x4 accg[4][4], accu[4][4];
#pragma unroll
  for (int i = 0; i < 4; ++i)
#pragma unroll
    for (int j = 0; j < 4; ++j) {
      accg[i][j] = (f32x4){0.f, 0.f, 0.f, 0.f};
      accu[i][j] = (f32x4){0.f, 0.f, 0.f, 0.f};
    }

  const bf16_t* Ab = Xg + (size_t)m0 * DM;
  const bf16_t* Gb = Wgt + ((size_t)e * IM + n0) * DM;
  const bf16_t* Ub = Wut + ((size_t)e * IM + n0) * DM;

  for (int k0 = 0; k0 < DM; k0 += 64) {
    __syncthreads();
#pragma unroll
    for (int it = 0; it < 4; ++it) {
      int c = it * 256 + tid;                 // 16B chunk id; LDS contiguous per wave
      int r = c >> 3, c8 = c & 7;             // 8 chunks per 64-elem row
      size_t go = (size_t)r * DM + k0 + c8 * 8;
      async_cp16(Ab + go, sA + c * 8);
      async_cp16(Gb + go, sG + c * 8);
      async_cp16(Ub + go, sU + c * 8);
    }
    __syncthreads();
#pragma unroll
    for (int s = 0; s < 2; ++s) {
      bf16x8 af[4], gf[4], uf[4];
#pragma unroll
      for (int i = 0; i < 4; ++i) {
        af[i] = *(const bf16x8*)(sA + (wm + i * 16 + fm) * 64 + s * 32 + fq * 8);
        gf[i] = *(const bf16x8*)(sG + (wn + i * 16 + fm) * 64 + s * 32 + fq * 8);
        uf[i] = *(const bf16x8*)(sU + (wn + i * 16 + fm) * 64 + s * 32 + fq * 8);
      }
#pragma unroll
      for (int i = 0; i < 4; ++i)
#pragma unroll
        for (int j = 0; j < 4; ++j) {
          accg[i][j] = __builtin_amdgcn_mfma_f32_16x16x32_bf16(af[i], gf[j], accg[i][j], 0, 0, 0);
          accu[i][j] = __builtin_amdgcn_mfma_f32_16x16x32_bf16(af[i], uf[j], accu[i][j], 0, 0, 0);
        }
    }
  }
  // epilogue: silu(g)*u -> bf16 H. C/D layout: col=lane&15, row=fq*4+reg (m89-verified)
#pragma unroll
  for (int i = 0; i < 4; ++i) {
#pragma unroll
    for (int r = 0; r < 4; ++r) {
      int lm = wm + i * 16 + fq * 4 + r;
      if (mt * 128 + lm < ne) {
        bf16_t* hrow = H + (size_t)(m0 + lm) * IM + n0 + wn;
#pragma unroll
        for (int j = 0; j < 4; ++j) {
          float g = accg[i][j][r], u = accu[i][j][r];
          float h = g * __builtin_amdgcn_rcpf(1.f + __expf(-g)) * u;
          hrow[j * 16 + fm] = (bf16_t)h;
        }
      }
    }
  }
}

// ---------------- GEMM2: out[token] += w_slot * (H @ WdT') per expert
__global__ __launch_bounds__(256, 2) void gemm2_kernel(
    const bf16_t* __restrict__ H, const bf16_t* __restrict__ Wdt,
    const int* __restrict__ offsets, const int* __restrict__ slot_token,
    const float* __restrict__ slot_w, float* __restrict__ out) {
  int e = blockIdx.z, mt = blockIdx.y, nt = blockIdx.x;
  int row0 = offsets[e], ne = offsets[e + 1] - row0;
  if (mt * 128 >= ne) return;
  int m0 = row0 + mt * 128;
  int n0 = nt * 128;

  __shared__ bf16_t sA[128 * 64];
  __shared__ bf16_t sB[128 * 64];

  int tid = threadIdx.x, lane = tid & 63, wv = tid >> 6;
  int fm = lane & 15, fq = lane >> 4;
  int wm = (wv & 1) * 64, wn = (wv >> 1) * 64;

  f32x4 acc[4][4];
#pragma unroll
  for (int i = 0; i < 4; ++i)
#pragma unroll
    for (int j = 0; j < 4; ++j) acc[i][j] = (f32x4){0.f, 0.f, 0.f, 0.f};

  const bf16_t* Ab = H + (size_t)m0 * IM;
  const bf16_t* Bb = Wdt + ((size_t)e * DM + n0) * IM;

  for (int k0 = 0; k0 < IM; k0 += 64) {
    __syncthreads();
#pragma unroll
    for (int it = 0; it < 4; ++it) {
      int c = it * 256 + tid;
      int r = c >> 3, c8 = c & 7;
      size_t go = (size_t)r * IM + k0 + c8 * 8;
      async_cp16(Ab + go, sA + c * 8);
      async_cp16(Bb + go, sB + c * 8);
    }
    __syncthreads();
#pragma unroll
    for (int s = 0; s < 2; ++s) {
      bf16x8 af[4], bf[4];
#pragma unroll
      for (int i = 0; i < 4; ++i) {
        af[i] = *(const bf16x8*)(sA + (wm + i * 16 + fm) * 64 + s * 32 + fq * 8);
        bf[i] = *(const bf16x8*)(sB + (wn + i * 16 + fm) * 64 + s * 32 + fq * 8);
      }
#pragma unroll
      for (int i = 0; i < 4; ++i)
#pragma unroll
        for (int j = 0; j < 4; ++j)
          acc[i][j] = __builtin_amdgcn_mfma_f32_16x16x32_bf16(af[i], bf[j], acc[i][j], 0, 0, 0);
    }
  }
#pragma unroll
  for (int i = 0; i < 4; ++i) {
#pragma unroll
    for (int r = 0; r < 4; ++r) {
      int lm = wm + i * 16 + fq * 4 + r;
      if (mt * 128 + lm < ne) {
        int slot = m0 + lm;
        float w = slot_w[slot];
        int tok = slot_token[slot];
        float* orow = out + (size_t)tok * DM + n0 + wn;
#pragma unroll
        for (int j = 0; j < 4; ++j)
          atomicAdd(orow + j * 16 + fm, acc[i][j][r] * w);
      }
    }
  }
}

// ---------------- workspace layout (bytes)
static constexpr size_t OFF_TOPKI = 256;                               // [NT][2] i32
static constexpr size_t OFF_TOPKW = OFF_TOPKI + (size_t)NT * 2 * 4;    // [NT][2] f32
static constexpr size_t OFF_STOK  = OFF_TOPKW + (size_t)NT * 2 * 4;    // [NS] i32
static constexpr size_t OFF_SW    = OFF_STOK + (size_t)NS * 4;         // [NS] f32
static constexpr size_t OFF_XG    = OFF_SW + (size_t)NS * 4;           // [SCAP][DM] bf16
static constexpr size_t OFF_H     = OFF_XG + (size_t)SCAP * DM * 2;    // [SCAP][IM] bf16
static constexpr size_t OFF_WGT   = OFF_H + (size_t)SCAP * IM * 2;     // [NE][IM][DM] bf16
static constexpr size_t OFF_WUT   = OFF_WGT + (size_t)NE * IM * DM * 2;
static constexpr size_t OFF_WDT   = OFF_WUT + (size_t)NE * IM * DM * 2; // [NE][DM][IM] bf16

extern "C" void kernel_launch(void* const* d_in, const int* in_sizes, int n_in,
                              void* d_out, int out_size, void* d_ws, size_t ws_size,
                              hipStream_t stream) {
  const float* x      = (const float*)d_in[0];
  const float* w_gate = (const float*)d_in[1];
  const float* wg     = (const float*)d_in[2];
  const float* wu     = (const float*)d_in[3];
  const float* wd     = (const float*)d_in[4];
  float* out = (float*)d_out;

  char* ws = (char*)d_ws;
  int*   counts   = (int*)(ws + 0);
  int*   cursors  = (int*)(ws + 32);
  int*   offsets  = (int*)(ws + 64);
  float* prob_sum = (float*)(ws + 128);
  int*   topk_idx = (int*)(ws + OFF_TOPKI);
  float* topk_w   = (float*)(ws + OFF_TOPKW);
  int*   slot_tok = (int*)(ws + OFF_STOK);
  float* slot_w   = (float*)(ws + OFF_SW);
  bf16_t* Xg  = (bf16_t*)(ws + OFF_XG);
  bf16_t* Hb  = (bf16_t*)(ws + OFF_H);
  bf16_t* Wgt = (bf16_t*)(ws + OFF_WGT);
  bf16_t* Wut = (bf16_t*)(ws + OFF_WUT);
  bf16_t* Wdt = (bf16_t*)(ws + OFF_WDT);

  hipMemsetAsync(d_out, 0, (size_t)out_size * 4, stream);
  hipMemsetAsync(ws, 0, 256, stream);

  // weight convert+transpose to [n][k] bf16
  transpose_cvt<<<dim3(IM / 32, DM / 32, NE), dim3(32, 8), 0, stream>>>(wg, Wgt, DM, IM);
  transpose_cvt<<<dim3(IM / 32, DM / 32, NE), dim3(32, 8), 0, stream>>>(wu, Wut, DM, IM);
  transpose_cvt<<<dim3(DM / 32, IM / 32, NE), dim3(32, 8), 0, stream>>>(wd, Wdt, IM, DM);

  router_kernel<<<NT / 32, 256, 0, stream>>>(x, w_gate, counts, prob_sum, topk_idx, topk_w);
  scan_aux<<<1, 64, 0, stream>>>(counts, prob_sum, offsets, cursors, out + (out_size - 1));
  gather_kernel<<<NS / 4, 256, 0, stream>>>(x, topk_idx, topk_w, cursors, slot_tok, slot_w, Xg);

  // capacity grid (64 M-tiles/expert = worst case); inactive tiles early-exit
  gemm1_kernel<<<dim3(IM / 128, 64, NE), 256, 0, stream>>>(Xg, Wgt, Wut, Hb, offsets);
  gemm2_kernel<<<dim3(DM / 128, 64, NE), 256, 0, stream>>>(Hb, Wdt, offsets, slot_tok, slot_w, out);
}

// Round 2
// 1248.922 us; speedup vs baseline: 1.0865x; 1.0865x over previous
//
#include <hip/hip_runtime.h>
#include <hip/hip_bf16.h>
#include <cstdint>
#include <cstddef>

#define NE 8          // experts
#define TK 2          // top-k
#define DM 1024       // hidden
#define IM 4096       // intermediate
#define NT 8192       // tokens (4*2048)
#define NS (NT*TK)    // total slots = 16384 (exact)
#define SCAP (NS+128) // padded rows for last-tile overhang

typedef __bf16 bf16_t;
typedef __bf16 bf16x8 __attribute__((ext_vector_type(8)));
typedef __bf16 bf16x4 __attribute__((ext_vector_type(4)));
typedef float f32x4 __attribute__((ext_vector_type(4)));

// async global->LDS, 16B per lane. LDS side must be wave-uniform base + lane*16.
__device__ __forceinline__ void async_cp16(const bf16_t* g, bf16_t* l) {
  __builtin_amdgcn_global_load_lds(
      (__attribute__((address_space(1))) void*)(const_cast<bf16_t*>(g)),
      (__attribute__((address_space(3))) void*)(l), 16, 0, 0);
}

// ---------------- transpose + fp32->bf16 convert: src [z][R][C] f32 -> dst [z][C][R] bf16
__global__ void transpose_cvt(const float* __restrict__ src, bf16_t* __restrict__ dst,
                              int R, int C) {
  __shared__ float t[32][33];
  int bx = blockIdx.x * 32, by = blockIdx.y * 32;
  size_t zb = (size_t)blockIdx.z * R * C;
  int tx = threadIdx.x, ty = threadIdx.y;   // 32 x 8
#pragma unroll
  for (int i = 0; i < 4; ++i)
    t[ty + i*8][tx] = src[zb + (size_t)(by + ty + i*8) * C + bx + tx];
  __syncthreads();
#pragma unroll
  for (int i = 0; i < 4; ++i)
    dst[zb + (size_t)(bx + ty + i*8) * R + by + tx] = (bf16_t)t[tx][ty + i*8];
}

// ---------------- router: logits, softmax, top-2, renorm; per-expert counts + prob sums
__global__ void router_kernel(const float* __restrict__ x, const float* __restrict__ wgate,
                              int* __restrict__ counts, float* __restrict__ prob_sum,
                              int* __restrict__ topk_idx, float* __restrict__ topk_w) {
  __shared__ float s_psum[NE];
  __shared__ int s_cnt[NE];
  int tid = threadIdx.x;
  if (tid < NE) { s_psum[tid] = 0.f; s_cnt[tid] = 0; }
  __syncthreads();
  int lane = tid & 63, wv = tid >> 6;
  for (int t = 0; t < 8; ++t) {             // 4 waves x 8 tokens = 32 tokens/block
    int n = blockIdx.x * 32 + wv * 8 + t;
    float acc[NE];
#pragma unroll
    for (int e = 0; e < NE; ++e) acc[e] = 0.f;
#pragma unroll
    for (int j = 0; j < 16; ++j) {
      int d = j * 64 + lane;
      float xv = x[(size_t)n * DM + d];
#pragma unroll
      for (int e = 0; e < NE; ++e) acc[e] += xv * wgate[e * DM + d];
    }
#pragma unroll
    for (int e = 0; e < NE; ++e) {
#pragma unroll
      for (int off = 32; off > 0; off >>= 1) acc[e] += __shfl_xor(acc[e], off);
    }
    if (lane == 0) {
      float mx = acc[0];
#pragma unroll
      for (int e = 1; e < NE; ++e) mx = fmaxf(mx, acc[e]);
      float p[NE], s = 0.f;
#pragma unroll
      for (int e = 0; e < NE; ++e) { p[e] = __expf(acc[e] - mx); s += p[e]; }
      float inv = 1.f / s;
#pragma unroll
      for (int e = 0; e < NE; ++e) p[e] *= inv;
      int i0 = 0;
      for (int e = 1; e < NE; ++e) if (p[e] > p[i0]) i0 = e;     // ties -> lower idx (matches top_k)
      int i1 = (i0 == 0) ? 1 : 0;
      for (int e = 0; e < NE; ++e) if (e != i0 && p[e] > p[i1]) i1 = e;
      float rs = 1.f / (p[i0] + p[i1]);
      topk_idx[n * 2 + 0] = i0; topk_idx[n * 2 + 1] = i1;
      topk_w[n * 2 + 0] = p[i0] * rs; topk_w[n * 2 + 1] = p[i1] * rs;
      atomicAdd(&s_cnt[i0], 1); atomicAdd(&s_cnt[i1], 1);
#pragma unroll
      for (int e = 0; e < NE; ++e) atomicAdd(&s_psum[e], p[e]);
    }
  }
  __syncthreads();
  if (tid < NE) { atomicAdd(&counts[tid], s_cnt[tid]); atomicAdd(&prob_sum[tid], s_psum[tid]); }
}

// ---------------- exclusive scan of counts (8 elems), cursors, aux loss
__global__ void scan_aux(const int* __restrict__ counts, const float* __restrict__ prob_sum,
                         int* __restrict__ offsets, int* __restrict__ cursors,
                         float* __restrict__ aux_out) {
  if (threadIdx.x == 0) {
    int off = 0;
    float aux = 0.f;
    for (int e = 0; e < NE; ++e) {
      offsets[e] = off; cursors[e] = off;
      float f = (float)counts[e] * (1.f / (float)NS);
      float p = prob_sum[e] * (1.f / (float)NT);
      aux += f * p;
      off += counts[e];
    }
    offsets[NE] = off;
    *aux_out = 0.02f * 8.f * aux;
  }
}

// ---------------- gather tokens into per-expert compact bf16 rows
__global__ void gather_kernel(const float* __restrict__ x, const int* __restrict__ topk_idx,
                              const float* __restrict__ topk_w, int* __restrict__ cursors,
                              int* __restrict__ slot_token, float* __restrict__ slot_w,
                              int* __restrict__ pair_slot, bf16_t* __restrict__ Xg) {
  int lane = threadIdx.x & 63, wv = threadIdx.x >> 6;
  int pair = blockIdx.x * 4 + wv;           // (token, k)
  int n = pair >> 1, k = pair & 1;
  int e = topk_idx[n * 2 + k];
  int slot = 0;
  if (lane == 0) slot = atomicAdd(&cursors[e], 1);
  slot = __shfl(slot, 0);
  if (lane == 0) {
    slot_token[slot] = n; slot_w[slot] = topk_w[n * 2 + k];
    pair_slot[pair] = slot;
  }
#pragma unroll
  for (int j = 0; j < 16; ++j) {
    int d = j * 64 + lane;
    Xg[(size_t)slot * DM + d] = (bf16_t)x[(size_t)n * DM + d];
  }
}

// ---------------- GEMM1: H = silu(Xg @ WgT') * (Xg @ WuT')  per expert, bf16 MFMA
// LDS XOR-swizzle: LDS[r][c8] holds global chunk [r][c8 ^ (r&7)]; frag read re-applies XOR.
__global__ __launch_bounds__(256, 2) void gemm1_kernel(
    const bf16_t* __restrict__ Xg, const bf16_t* __restrict__ Wgt,
    const bf16_t* __restrict__ Wut, bf16_t* __restrict__ H,
    const int* __restrict__ offsets) {
  int e = blockIdx.z, mt = blockIdx.y, nt = blockIdx.x;
  int row0 = offsets[e], ne = offsets[e + 1] - row0;
  if (mt * 128 >= ne) return;
  int m0 = row0 + mt * 128;
  int n0 = nt * 128;

  __shared__ bf16_t sA[128 * 64];
  __shared__ bf16_t sG[128 * 64];
  __shared__ bf16_t sU[128 * 64];

  int tid = threadIdx.x, lane = tid & 63, wv = tid >> 6;
  int fm = lane & 15, fq = lane >> 4;
  int wm = (wv & 1) * 64, wn = (wv >> 1) * 64;

  f32x4 accg[4][4], accu[4][4];
#pragma unroll
  for (int i = 0; i < 4; ++i)
#pragma unroll
    for (int j = 0; j < 4; ++j) {
      accg[i][j] = (f32x4){0.f, 0.f, 0.f, 0.f};
      accu[i][j] = (f32x4){0.f, 0.f, 0.f, 0.f};
    }

  const bf16_t* Ab = Xg + (size_t)m0 * DM;
  const bf16_t* Gb = Wgt + ((size_t)e * IM + n0) * DM;
  const bf16_t* Ub = Wut + ((size_t)e * IM + n0) * DM;

  for (int k0 = 0; k0 < DM; k0 += 64) {
    __syncthreads();
#pragma unroll
    for (int it = 0; it < 4; ++it) {
      int c = it * 256 + tid;                 // 16B chunk id; LDS contiguous per wave
      int r = c >> 3, c8 = c & 7;             // 8 chunks per 64-elem row
      int gc8 = c8 ^ (r & 7);                 // inverse swizzle on global source
      size_t go = (size_t)r * DM + k0 + gc8 * 8;
      async_cp16(Ab + go, sA + c * 8);
      async_cp16(Gb + go, sG + c * 8);
      async_cp16(Ub + go, sU + c * 8);
    }
    __syncthreads();
#pragma unroll
    for (int s = 0; s < 2; ++s) {
      bf16x8 af[4], gf[4], uf[4];
      int q = s * 4 + fq;
#pragma unroll
      for (int i = 0; i < 4; ++i) {
        int ra = wm + i * 16 + fm;
        int rb = wn + i * 16 + fm;
        af[i] = *(const bf16x8*)(sA + ra * 64 + (q ^ (ra & 7)) * 8);
        gf[i] = *(const bf16x8*)(sG + rb * 64 + (q ^ (rb & 7)) * 8);
        uf[i] = *(const bf16x8*)(sU + rb * 64 + (q ^ (rb & 7)) * 8);
      }
#pragma unroll
      for (int i = 0; i < 4; ++i)
#pragma unroll
        for (int j = 0; j < 4; ++j) {
          accg[i][j] = __builtin_amdgcn_mfma_f32_16x16x32_bf16(af[i], gf[j], accg[i][j], 0, 0, 0);
          accu[i][j] = __builtin_amdgcn_mfma_f32_16x16x32_bf16(af[i], uf[j], accu[i][j], 0, 0, 0);
        }
    }
  }
  // epilogue: silu(g)*u -> bf16 H. C/D layout: col=lane&15, row=fq*4+reg (m89-verified)
#pragma unroll
  for (int i = 0; i < 4; ++i) {
#pragma unroll
    for (int r = 0; r < 4; ++r) {
      int lm = wm + i * 16 + fq * 4 + r;
      if (mt * 128 + lm < ne) {
        bf16_t* hrow = H + (size_t)(m0 + lm) * IM + n0 + wn;
#pragma unroll
        for (int j = 0; j < 4; ++j) {
          float g = accg[i][j][r], u = accu[i][j][r];
          float h = g * __builtin_amdgcn_rcpf(1.f + __expf(-g)) * u;
          hrow[j * 16 + fm] = (bf16_t)h;
        }
      }
    }
  }
}

// ---------------- GEMM2: Y[slot] = H[slot] @ WdT' (unweighted, bf16 out; combine applies weights)
__global__ __launch_bounds__(256, 2) void gemm2_kernel(
    const bf16_t* __restrict__ H, const bf16_t* __restrict__ Wdt,
    const int* __restrict__ offsets, bf16_t* __restrict__ Y) {
  int e = blockIdx.z, mt = blockIdx.y, nt = blockIdx.x;
  int row0 = offsets[e], ne = offsets[e + 1] - row0;
  if (mt * 128 >= ne) return;
  int m0 = row0 + mt * 128;
  int n0 = nt * 128;

  __shared__ bf16_t sA[128 * 64];
  __shared__ bf16_t sB[128 * 64];

  int tid = threadIdx.x, lane = tid & 63, wv = tid >> 6;
  int fm = lane & 15, fq = lane >> 4;
  int wm = (wv & 1) * 64, wn = (wv >> 1) * 64;

  f32x4 acc[4][4];
#pragma unroll
  for (int i = 0; i < 4; ++i)
#pragma unroll
    for (int j = 0; j < 4; ++j) acc[i][j] = (f32x4){0.f, 0.f, 0.f, 0.f};

  const bf16_t* Ab = H + (size_t)m0 * IM;
  const bf16_t* Bb = Wdt + ((size_t)e * DM + n0) * IM;

  for (int k0 = 0; k0 < IM; k0 += 64) {
    __syncthreads();
#pragma unroll
    for (int it = 0; it < 4; ++it) {
      int c = it * 256 + tid;
      int r = c >> 3, c8 = c & 7;
      int gc8 = c8 ^ (r & 7);
      size_t go = (size_t)r * IM + k0 + gc8 * 8;
      async_cp16(Ab + go, sA + c * 8);
      async_cp16(Bb + go, sB + c * 8);
    }
    __syncthreads();
#pragma unroll
    for (int s = 0; s < 2; ++s) {
      bf16x8 af[4], bf[4];
      int q = s * 4 + fq;
#pragma unroll
      for (int i = 0; i < 4; ++i) {
        int ra = wm + i * 16 + fm;
        int rb = wn + i * 16 + fm;
        af[i] = *(const bf16x8*)(sA + ra * 64 + (q ^ (ra & 7)) * 8);
        bf[i] = *(const bf16x8*)(sB + rb * 64 + (q ^ (rb & 7)) * 8);
      }
#pragma unroll
      for (int i = 0; i < 4; ++i)
#pragma unroll
        for (int j = 0; j < 4; ++j)
          acc[i][j] = __builtin_amdgcn_mfma_f32_16x16x32_bf16(af[i], bf[j], acc[i][j], 0, 0, 0);
    }
  }
#pragma unroll
  for (int i = 0; i < 4; ++i) {
#pragma unroll
    for (int r = 0; r < 4; ++r) {
      int lm = wm + i * 16 + fq * 4 + r;
      if (mt * 128 + lm < ne) {
        bf16_t* yrow = Y + (size_t)(m0 + lm) * DM + n0 + wn;
#pragma unroll
        for (int j = 0; j < 4; ++j)
          yrow[j * 16 + fm] = (bf16_t)acc[i][j][r];
      }
    }
  }
}

// ---------------- combine: out[n] = w0 * Y[slot(n,0)] + w1 * Y[slot(n,1)]
__global__ void combine_kernel(const bf16_t* __restrict__ Y, const int* __restrict__ pair_slot,
                               const float* __restrict__ topk_w, float* __restrict__ out) {
  int n = blockIdx.x;
  int t = threadIdx.x;
  int s0 = pair_slot[n * 2 + 0], s1 = pair_slot[n * 2 + 1];
  float w0 = topk_w[n * 2 + 0], w1 = topk_w[n * 2 + 1];
  bf16x4 y0 = *(const bf16x4*)(Y + (size_t)s0 * DM + t * 4);
  bf16x4 y1 = *(const bf16x4*)(Y + (size_t)s1 * DM + t * 4);
  float4 o;
  o.x = w0 * (float)y0[0] + w1 * (float)y1[0];
  o.y = w0 * (float)y0[1] + w1 * (float)y1[1];
  o.z = w0 * (float)y0[2] + w1 * (float)y1[2];
  o.w = w0 * (float)y0[3] + w1 * (float)y1[3];
  *(float4*)(out + (size_t)n * DM + t * 4) = o;
}

// ---------------- workspace layout (bytes)
static constexpr size_t OFF_TOPKI = 256;                               // [NT][2] i32
static constexpr size_t OFF_TOPKW = OFF_TOPKI + (size_t)NT * 2 * 4;    // [NT][2] f32
static constexpr size_t OFF_STOK  = OFF_TOPKW + (size_t)NT * 2 * 4;    // [NS] i32
static constexpr size_t OFF_SW    = OFF_STOK + (size_t)NS * 4;         // [NS] f32
static constexpr size_t OFF_PSLOT = OFF_SW + (size_t)NS * 4;           // [NS] i32
static constexpr size_t OFF_XG    = OFF_PSLOT + (size_t)NS * 4;        // [SCAP][DM] bf16 (Y aliases)
static constexpr size_t OFF_H     = OFF_XG + (size_t)SCAP * DM * 2;    // [SCAP][IM] bf16
static constexpr size_t OFF_WGT   = OFF_H + (size_t)SCAP * IM * 2;     // [NE][IM][DM] bf16
static constexpr size_t OFF_WUT   = OFF_WGT + (size_t)NE * IM * DM * 2;
static constexpr size_t OFF_WDT   = OFF_WUT + (size_t)NE * IM * DM * 2; // [NE][DM][IM] bf16

extern "C" void kernel_launch(void* const* d_in, const int* in_sizes, int n_in,
                              void* d_out, int out_size, void* d_ws, size_t ws_size,
                              hipStream_t stream) {
  const float* x      = (const float*)d_in[0];
  const float* w_gate = (const float*)d_in[1];
  const float* wg     = (const float*)d_in[2];
  const float* wu     = (const float*)d_in[3];
  const float* wd     = (const float*)d_in[4];
  float* out = (float*)d_out;

  char* ws = (char*)d_ws;
  int*   counts   = (int*)(ws + 0);
  int*   cursors  = (int*)(ws + 32);
  int*   offsets  = (int*)(ws + 64);
  float* prob_sum = (float*)(ws + 128);
  int*   topk_idx = (int*)(ws + OFF_TOPKI);
  float* topk_w   = (float*)(ws + OFF_TOPKW);
  int*   slot_tok = (int*)(ws + OFF_STOK);
  float* slot_w   = (float*)(ws + OFF_SW);
  int*   pair_slot= (int*)(ws + OFF_PSLOT);
  bf16_t* Xg  = (bf16_t*)(ws + OFF_XG);
  bf16_t* Yb  = Xg;                          // Y aliases Xg (dead after gemm1; same size)
  bf16_t* Hb  = (bf16_t*)(ws + OFF_H);
  bf16_t* Wgt = (bf16_t*)(ws + OFF_WGT);
  bf16_t* Wut = (bf16_t*)(ws + OFF_WUT);
  bf16_t* Wdt = (bf16_t*)(ws + OFF_WDT);

  hipMemsetAsync(ws, 0, 256, stream);

  // weight convert+transpose to [n][k] bf16
  transpose_cvt<<<dim3(IM / 32, DM / 32, NE), dim3(32, 8), 0, stream>>>(wg, Wgt, DM, IM);
  transpose_cvt<<<dim3(IM / 32, DM / 32, NE), dim3(32, 8), 0, stream>>>(wu, Wut, DM, IM);
  transpose_cvt<<<dim3(DM / 32, IM / 32, NE), dim3(32, 8), 0, stream>>>(wd, Wdt, IM, DM);

  router_kernel<<<NT / 32, 256, 0, stream>>>(x, w_gate, counts, prob_sum, topk_idx, topk_w);
  scan_aux<<<1, 64, 0, stream>>>(counts, prob_sum, offsets, cursors, out + (out_size - 1));
  gather_kernel<<<NS / 4, 256, 0, stream>>>(x, topk_idx, topk_w, cursors, slot_tok, slot_w,
                                            pair_slot, Xg);

  // capacity grid (64 M-tiles/expert = worst case); inactive tiles early-exit
  gemm1_kernel<<<dim3(IM / 128, 64, NE), 256, 0, stream>>>(Xg, Wgt, Wut, Hb, offsets);
  gemm2_kernel<<<dim3(DM / 128, 64, NE), 256, 0, stream>>>(Hb, Wdt, offsets, Yb);
  combine_kernel<<<NT, 256, 0, stream>>>(Yb, pair_slot, topk_w, out);
}